// Round 20
// baseline (130.882 us; speedup 1.0000x reference)
//
#include <hip/hip_runtime.h>
#include <hip/hip_fp16.h>
#include <math.h>
#include <stdint.h>

// VocosISTFTHead on MI355X.
//  K0 convert_AB: fused. Blocks <2048: hs -> Af fp16 plane + Nyquist spec col
//                 (full f32 dot) -> coeffs slot[1]. Blocks >=2048: W -> tiled
//                 fp16 plane Whi [yb4][kt16][r256][k32].
//  K1 gemm_mfma : spec = hs @ W.T + b via single fp16 MFMA (Af x Whi).
//                 256 rows x 128 pairs, 512 thr / 8 waves, 4-buffer A ring,
//                 barrier every 2 K-steps (round-19 structure, proven <48us).
//  K2 fft_oa    : fused irfft+window+overlap-add, rolling 8-slot ring.
//                 ROUND 20: IN-PLACE Stockham stages (register staging; safe:
//                 one wave's 8 ds_reads all issue before any ds_write, DS pipe
//                 in-order, same-pointer aliasing pins compiler order) -> bB
//                 eliminated, LDS 53.2 -> 34.8KB -> 4 blocks/CU; grid grown to
//                 use the slot: JB=57, RND=9 (36 spans/block, 912 blocks =
//                 3.56/CU effective vs 2.94).
// coeffs row layout (1024 halves, 2048B aligned): [0]=DC real, [1]=Nyquist real,
//   complex k (k=1..511) at halves [2k, 2k+2).
// ws: [0 : 33.55M) Af | [33.55M : 34.60M) Whi | [67.11M : 134.22M) coeffs fp16

#define FRAMES  32768
#define TWO_PI  6.283185307179586f
#define SPR 4      // spans per round
#define RND 9      // rounds per block (36 spans)
#define JB  57     // blocks per batch (spans 0..2051 >= needed 2050)

typedef unsigned short ushort_t;
typedef __attribute__((ext_vector_type(8))) _Float16 f16x8;
typedef __attribute__((ext_vector_type(4))) float f32x4;

#define GLDS(gp, lp) __builtin_amdgcn_global_load_lds( \
    (const __attribute__((address_space(1))) void*)(gp), \
    (__attribute__((address_space(3))) void*)(lp), 16, 0, 0)

__device__ __forceinline__ float2 f2(float x, float y){ return make_float2(x,y); }
__device__ __forceinline__ float2 cadd(float2 a, float2 b){ return f2(a.x+b.x, a.y+b.y); }
__device__ __forceinline__ float2 csub(float2 a, float2 b){ return f2(a.x-b.x, a.y-b.y); }
__device__ __forceinline__ float2 cmul(float2 a, float2 b){ return f2(a.x*b.x - a.y*b.y, a.x*b.y + a.y*b.x); }

__device__ __forceinline__ uint32_t pack2h(float a, float b) {
  const ushort_t ha = __half_as_ushort(__float2half_rn(a));
  const ushort_t hb = __half_as_ushort(__float2half_rn(b));
  return (uint32_t)ha | ((uint32_t)hb << 16);
}

// ---------------------------------------------------------------------------
// K0: fused A/B conversion (unchanged, verified).
// ---------------------------------------------------------------------------
__global__ __launch_bounds__(256) void convert_AB(
    const float* __restrict__ hs, const float* __restrict__ Wm,
    const float* __restrict__ bias, ushort_t* __restrict__ Af,
    ushort_t* __restrict__ Whi, __half* __restrict__ coeffs)
{
  const int bid = blockIdx.x;
  const int t = threadIdx.x;
  if (bid < 2048) {
    const int r = t >> 4, c = t & 15;
    const int m = bid * 16 + r;
    const float* src = hs + (size_t)m * 512 + c * 32;
    const float* wm  = Wm + (size_t)512  * 512 + c * 32;
    const float* wp  = Wm + (size_t)1025 * 512 + c * 32;

    float v[32];
    #pragma unroll
    for (int i = 0; i < 8; ++i) *(float4*)&v[i*4] = *(const float4*)(src + i*4);

    float dm = 0.f, dp = 0.f;
    #pragma unroll
    for (int i = 0; i < 8; ++i) {
      const float4 a  = *(const float4*)&v[i*4];
      const float4 m4 = *(const float4*)(wm + i*4);
      const float4 p4 = *(const float4*)(wp + i*4);
      dm = fmaf(a.x,m4.x, fmaf(a.y,m4.y, fmaf(a.z,m4.z, fmaf(a.w,m4.w, dm))));
      dp = fmaf(a.x,p4.x, fmaf(a.y,p4.y, fmaf(a.z,p4.z, fmaf(a.w,p4.w, dp))));
    }

    uint32_t hu[16];
    #pragma unroll
    for (int i = 0; i < 16; ++i) hu[i] = pack2h(v[2*i], v[2*i+1]);
    ushort_t* dh = Af + (size_t)m * 512 + c * 32;
    #pragma unroll
    for (int q = 0; q < 4; ++q)
      *(uint4*)(dh + q*8) = make_uint4(hu[4*q], hu[4*q+1], hu[4*q+2], hu[4*q+3]);

    #pragma unroll
    for (int off = 8; off; off >>= 1) {
      dm += __shfl_xor(dm, off, 16);
      dp += __shfl_xor(dp, off, 16);
    }
    if (c == 0) {
      const float sm = dm + bias[512], sp = dp + bias[1025];
      const float mag = fminf(__expf(sm), 100.0f);
      coeffs[(size_t)m * 1024 + 1] = __float2half_rn(mag * __cosf(sp));
    }
  } else {
    const int gid = (bid - 2048) * 256 + t;
    const int sd = gid & 3;
    const int r  = (gid >> 2) & 255;
    const int kt = (gid >> 10) & 15;
    const int yb = gid >> 14;                        // 0..3
    const int srow = (r < 128) ? (yb*128 + r) : (513 + yb*128 + (r - 128));
    const float* src = Wm + (size_t)srow * 512 + kt*32 + sd*8;
    const float4 a = *(const float4*)src;
    const float4 b = *(const float4*)(src + 4);
    const uint4 o = make_uint4(pack2h(a.x,a.y), pack2h(a.z,a.w),
                               pack2h(b.x,b.y), pack2h(b.z,b.w));
    *(uint4*)(Whi + (size_t)gid * 8) = o;
  }
}

// ---------------------------------------------------------------------------
// K1: MFMA GEMM (round-19 structure, unchanged: 4-buffer ring, 8 barriers).
// ---------------------------------------------------------------------------
__global__ __launch_bounds__(512, 2) void gemm_mfma(
    const ushort_t* __restrict__ Af, const ushort_t* __restrict__ Whi,
    const float* __restrict__ bias, __half* __restrict__ coeffs)
{
  __shared__ ushort_t Ab[32768];       // 4 bufs x (256r x 32k) fp16 = 64KB

  const int tid = threadIdx.x;
  const int w = tid >> 6, l = tid & 63;
  const int wr = w >> 2, wc = w & 3;         // wave grid 2M x 4N
  const int lc = l & 15, kg = l >> 4;        // frag row/col, k-octet

  const int bid = blockIdx.x;                // 512 = 8 XCD * 64
  const int swz = (bid & 7) * 64 + (bid >> 3);
  const int mb = swz >> 2, yb = swz & 3;     // 4 consecutive yb per mb per XCD

  uint32_t pa_off[2], lofs[2];
  #pragma unroll
  for (int ch = 0; ch < 2; ++ch) {
    const int g = ch*512 + tid;              // 0..1023
    const int r = g >> 2, sd = g & 3;
    lofs[ch] = r*32 + sd*8;                  // ushort units within a 16KB buf
    const int sl = sd ^ ((r >> 1) & 3);
    pa_off[ch] = (uint32_t)(mb*256 + r)*512 + sl*8;
  }
  uint32_t pb_off[4];
  #pragma unroll
  for (int cf = 0; cf < 4; ++cf) {
    const int rB = ((cf < 2) ? 0 : 128) + wc*32 + (cf & 1)*16 + lc;
    pb_off[cf] = (uint32_t)yb*131072u + rB*32 + kg*8;
  }

  f32x4 acc[8][4];                   // [rf][cf]: cf 0,1 mag; 2,3 phase
  #pragma unroll
  for (int rf = 0; rf < 8; ++rf)
    #pragma unroll
    for (int cf = 0; cf < 4; ++cf)
      #pragma unroll
      for (int q = 0; q < 4; ++q) acc[rf][cf][q] = 0.f;

  const int asl = (kg ^ ((lc >> 1) & 3)) * 8;

  f16x8 p[4], q[4];

#define WAITV2 asm volatile("s_waitcnt vmcnt(2) lgkmcnt(0)" ::: "memory")
#define WAITV4 asm volatile("s_waitcnt vmcnt(4) lgkmcnt(0)" ::: "memory")
#define SB     __builtin_amdgcn_s_barrier()
#define SCH0   __builtin_amdgcn_sched_barrier(0)

#define DSREAD(DST, BASE, RF0) do {                                      \
    _Pragma("unroll")                                                    \
    for (int r4 = 0; r4 < 4; ++r4) {                                     \
      const int rr = wr*128 + ((RF0) + r4)*16 + lc;                      \
      DST[r4] = *(const f16x8*)(&Ab[(BASE) + rr*32 + asl]);              \
    }                                                                    \
  } while (0)

#define MFMA16(FA, RF0, RB) do {                                         \
    __builtin_amdgcn_s_setprio(1);                                       \
    _Pragma("unroll")                                                    \
    for (int r4 = 0; r4 < 4; ++r4)                                       \
      _Pragma("unroll")                                                  \
      for (int cf = 0; cf < 4; ++cf)                                     \
        acc[(RF0)+r4][cf] = __builtin_amdgcn_mfma_f32_16x16x32_f16(      \
            FA[r4], RB[cf], acc[(RF0)+r4][cf], 0, 0, 0);                 \
    __builtin_amdgcn_s_setprio(0);                                       \
  } while (0)

  // Even-barrier certification: WAITV2 retires this wave's staging for
  // buf(kt) AND buf(kt+1) before it arrives; barrier release => both staged
  // chip-wide. Odd steps barrier-free. WAR: GLDS at step s targets buf(s-2),
  // whose reads finished before the intervening even barrier (lgkmcnt(0)).
#define ITER(KT, RBC, RBN, BAR) do {                                     \
    if (BAR) { WAITV2; SB; }                                             \
    DSREAD(p, aR, 0);                                                    \
    if ((KT) < 14) GLDS(Af + pa_off[0] + ((KT)+2)*32, &Ab[aW + lofs[0]]);\
    if ((KT) < 15) {                                                     \
      RBN[0] = *(const f16x8*)(Whi + pb_off[0] + ((KT)+1)*8192);         \
      RBN[1] = *(const f16x8*)(Whi + pb_off[1] + ((KT)+1)*8192);         \
    }                                                                    \
    DSREAD(q, aR, 4);                                                    \
    SCH0;                                                                \
    MFMA16(p, 0, RBC);                                                   \
    if ((KT) < 14) GLDS(Af + pa_off[1] + ((KT)+2)*32, &Ab[aW + lofs[1]]);\
    if ((KT) < 15) {                                                     \
      RBN[2] = *(const f16x8*)(Whi + pb_off[2] + ((KT)+1)*8192);         \
      RBN[3] = *(const f16x8*)(Whi + pb_off[3] + ((KT)+1)*8192);         \
    }                                                                    \
    SCH0;                                                                \
    MFMA16(q, 4, RBC);                                                   \
    { const unsigned t_ = aR; aR = aN; aN = aW; aW = aX; aX = t_; }      \
  } while (0)

  f16x8 rb0[4], rb1[4];
  GLDS(Af + pa_off[0], &Ab[lofs[0]]);
  GLDS(Af + pa_off[1], &Ab[lofs[1]]);
  GLDS(Af + pa_off[0] + 32, &Ab[8192 + lofs[0]]);
  GLDS(Af + pa_off[1] + 32, &Ab[8192 + lofs[1]]);
  SCH0;
  #pragma unroll
  for (int j = 0; j < 4; ++j) rb0[j] = *(const f16x8*)(Whi + pb_off[j]);
  SCH0;
  WAITV4;                              // retire buf0+buf1 chunks (keep B(0))
  SB;
  unsigned aR = 0, aN = 8192, aW = 16384, aX = 24576;

  ITER(0, rb0, rb1, 0);                // barrier provided by prologue
  ITER(1, rb1, rb0, 0);
  for (int k2 = 1; k2 < 8; ++k2) {
    ITER(2*k2,     rb0, rb1, 1);
    ITER(2*k2 + 1, rb1, rb0, 0);
  }
#undef ITER
#undef DSREAD
#undef MFMA16

  // Epilogue: j innermost so both 64B halves of each 128B line are adjacent.
  const int pc0 = yb*128 + wc*32 + lc;               // j=0 col, 0..511
  const int pc1 = pc0 + 16;                          // j=1 col, never 0
  const float bm0 = bias[pc0], bp0 = bias[513 + pc0];
  const float bm1 = bias[pc1], bp1 = bias[513 + pc1];
  #pragma unroll
  for (int rf = 0; rf < 8; ++rf) {
    const int rbase = mb*256 + wr*128 + rf*16 + kg*4;
    #pragma unroll
    for (int qi = 0; qi < 4; ++qi) {
      __half* row = coeffs + (size_t)(rbase + qi) * 1024;
      {
        const float sm = acc[rf][0][qi] + bm0;
        const float sp = acc[rf][2][qi] + bp0;
        const float mag = fminf(__expf(sm), 100.0f);
        const float aa = mag * __cosf(sp);
        const float bb = mag * __sinf(sp);
        if (pc0 == 0) row[0] = __float2half_rn(aa);  // DC real (imag dropped)
        else *(__half2*)(row + 2*pc0) = __float22half2_rn(make_float2(aa, bb));
      }
      {
        const float sm = acc[rf][1][qi] + bm1;
        const float sp = acc[rf][3][qi] + bp1;
        const float mag = fminf(__expf(sm), 100.0f);
        const float aa = mag * __cosf(sp);
        const float bb = mag * __sinf(sp);
        *(__half2*)(row + 2*pc1) = __float22half2_rn(make_float2(aa, bb));
      }
    }
  }
}

// ---------------------------------------------------------------------------
// K2: fused irfft + window + overlap-add, rolling ring, IN-PLACE FFT stages.
// ---------------------------------------------------------------------------
#define PIDX(s) ((s) + ((s) >> 3))
#define WFENCE  __builtin_amdgcn_wave_barrier()

// In-place stage: all 8 ds_reads issue before any ds_write (single wave
// instruction stream; DS pipe in-order; same-pointer aliasing pins the
// compiler). Register staging via v[8].
template<int NS>
__device__ __forceinline__ void stage_fft(float2* buf, int l, const float2* pw)
{
  float2 v[8];
  #pragma unroll
  for (int r = 0; r < 8; ++r) v[r] = buf[PIDX(l + 64*r)];
  if (NS > 1) {
    #pragma unroll
    for (int r = 1; r < 8; ++r) v[r] = cmul(v[r], pw[r-1]);
  }
  const float2 e0=v[0], e1=v[2], e2=v[4], e3=v[6];
  const float2 o0=v[1], o1=v[3], o2=v[5], o3=v[7];
  float2 a = cadd(e0,e2), b = csub(e0,e2), c = cadd(e1,e3), d = csub(e1,e3);
  const float2 E0 = cadd(a,c), E2 = csub(a,c);
  const float2 E1 = f2(b.x - d.y, b.y + d.x), E3 = f2(b.x + d.y, b.y - d.x);
  a = cadd(o0,o2); b = csub(o0,o2); c = cadd(o1,o3); d = csub(o1,o3);
  const float2 O0 = cadd(a,c), O2 = csub(a,c);
  const float2 O1 = f2(b.x - d.y, b.y + d.x), O3 = f2(b.x + d.y, b.y - d.x);
  const float r2 = 0.70710678118654752f;
  const float2 t0 = O0;
  const float2 t1 = f2(r2*(O1.x - O1.y),  r2*(O1.x + O1.y));
  const float2 t2 = f2(-O2.y, O2.x);
  const float2 t3 = f2(-r2*(O3.x + O3.y), r2*(O3.x - O3.y));
  float2 X[8];
  X[0]=cadd(E0,t0); X[4]=csub(E0,t0);
  X[1]=cadd(E1,t1); X[5]=csub(E1,t1);
  X[2]=cadd(E2,t2); X[6]=csub(E2,t2);
  X[3]=cadd(E3,t3); X[7]=csub(E3,t3);
  const int idxD = (l / NS) * (NS * 8) + (l & (NS-1));
  #pragma unroll
  for (int q = 0; q < 8; ++q) buf[PIDX(idxD + q*NS)] = X[q];
}

// Last stage (NS=64): windowed fp16 pairs straight into the ring slot.
__device__ __forceinline__ void stage_last(const float2* in, __half* frout,
                                           const float* __restrict__ window, int l,
                                           const float2* pw)
{
  float2 v[8];
  #pragma unroll
  for (int r = 0; r < 8; ++r) v[r] = in[PIDX(l + 64*r)];
  #pragma unroll
  for (int r = 1; r < 8; ++r) v[r] = cmul(v[r], pw[r-1]);
  const float2 e0=v[0], e1=v[2], e2=v[4], e3=v[6];
  const float2 o0=v[1], o1=v[3], o2=v[5], o3=v[7];
  float2 a = cadd(e0,e2), b = csub(e0,e2), c = cadd(e1,e3), d = csub(e1,e3);
  const float2 E0 = cadd(a,c), E2 = csub(a,c);
  const float2 E1 = f2(b.x - d.y, b.y + d.x), E3 = f2(b.x + d.y, b.y - d.x);
  a = cadd(o0,o2); b = csub(o0,o2); c = cadd(o1,o3); d = csub(o1,o3);
  const float2 O0 = cadd(a,c), O2 = csub(a,c);
  const float2 O1 = f2(b.x - d.y, b.y + d.x), O3 = f2(b.x + d.y, b.y - d.x);
  const float r2 = 0.70710678118654752f;
  const float2 t0 = O0;
  const float2 t1 = f2(r2*(O1.x - O1.y),  r2*(O1.x + O1.y));
  const float2 t2 = f2(-O2.y, O2.x);
  const float2 t3 = f2(-r2*(O3.x + O3.y), r2*(O3.x - O3.y));
  float2 X[8];
  X[0]=cadd(E0,t0); X[4]=csub(E0,t0);
  X[1]=cadd(E1,t1); X[5]=csub(E1,t1);
  X[2]=cadd(E2,t2); X[6]=csub(E2,t2);
  X[3]=cadd(E3,t3); X[7]=csub(E3,t3);
  #pragma unroll
  for (int q = 0; q < 8; ++q) {
    const int m = l + 64*q;
    const float2 wv = *(const float2*)(window + 2*m);
    *(__half2*)&frout[2*m] =
        __float22half2_rn(make_float2(X[q].x * wv.x, X[q].y * wv.y));
  }
}

__device__ __forceinline__ void fft_frame(const __half* __restrict__ cb, int F,
                                          float2* bAw, __half (*fr)[1024],
                                          const float2* twp, const float2* pw8,
                                          const float2* pwL,
                                          const float* __restrict__ window, int l)
{
  if (F < 0 || F > 2047) return;     // wave-uniform; stale slot never read
  const __half2* crow = (const __half2*)(cb + (size_t)F * 1024);
  const float sc = 1.0f / 1024.0f;
  #pragma unroll
  for (int jj = 0; jj < 4; ++jj) {
    const int k = 1 + l + 64*jj;
    const float2 Ck = __half22float2(crow[k]);
    const float2 Cq = __half22float2(crow[512-k]);
    const float cs = twp[jj].x, sn = twp[jj].y;
    const float Ex = sc*(Ck.x + Cq.x), Ey = sc*(Ck.y - Cq.y);
    const float Dx = Ck.x - Cq.x,      Dy = Ck.y + Cq.y;
    const float Ox = sc*(cs*Dx - sn*Dy), Oy = sc*(cs*Dy + sn*Dx);
    bAw[PIDX(k)]     = f2(Ex - Oy, Ey + Ox);
    bAw[PIDX(512-k)] = f2(Ex + Oy, Ox - Ey);
  }
  if (l == 0) {
    const float2 dn = __half22float2(crow[0]);   // (DC real, Nyq real)
    bAw[PIDX(0)] = f2(sc*(dn.x + dn.y), sc*(dn.x - dn.y));
  }
  WFENCE;
  stage_fft<1>(bAw, l, pw8);
  WFENCE;
  stage_fft<8>(bAw, l, pw8);
  WFENCE;
  stage_last(bAw, fr[F & 7], window, l, pwL);
  WFENCE;
}

__global__ __launch_bounds__(256) void fft_oa(
    const __half* __restrict__ coeffs, const float* __restrict__ window,
    float* __restrict__ out)
{
  __shared__ float2 bA[4][576];        // 18KB: per-wave FFT scratch (in-place)
  __shared__ __half fr[8][1024];       // 16KB: windowed-frame ring

  const int tid = threadIdx.x;
  const int w = tid >> 6, l = tid & 63;
  const int bid = blockIdx.x;
  const int b = bid / JB, j = bid - b * JB;
  const int T0 = SPR * RND * j;        // first span of this block

  const __half* cb = coeffs + (size_t)b * 2048 * 1024;
  float* outb = out + (size_t)b * 524288;

  // hoisted frame-invariant twiddles (18 sincos once per kernel)
  float2 twp[4], pw8[7], pwL[7];
  #pragma unroll
  for (int jj = 0; jj < 4; ++jj) {
    float sn, cs;
    __sincosf(TWO_PI * (1.0f/1024.0f) * (float)(1 + l + 64*jj), &sn, &cs);
    twp[jj] = f2(cs, sn);
  }
  {
    const float a8 = TWO_PI * (float)(l & 7) / 64.0f;
    const float aL = TWO_PI * (float)l / 512.0f;
    #pragma unroll
    for (int r = 1; r < 8; ++r) {
      float sn, cs;
      __sincosf(a8 * (float)r, &sn, &cs); pw8[r-1] = f2(cs, sn);
    }
    #pragma unroll
    for (int r = 1; r < 8; ++r) {
      float sn, cs;
      __sincosf(aL * (float)r, &sn, &cs); pwL[r-1] = f2(cs, sn);
    }
  }
  float wsq[4];
  #pragma unroll
  for (int i = 0; i < 4; ++i) {
    const float wv = window[tid + 256*i];
    wsq[i] = wv * wv;
  }
  const float rn = 1.0f / (wsq[0] + wsq[1] + wsq[2] + wsq[3]);  // interior norm

  // prologue: frames T0-3..T0-1 (waves 0-2)
  if (w < 3) fft_frame(cb, T0 - 3 + w, bA[w], fr, twp, pw8, pwL, window, l);

  for (int r = 0; r < RND; ++r) {
    // compute frames T0+4r+w into ring
    fft_frame(cb, T0 + SPR*r + w, bA[w], fr, twp, pw8, pwL, window, l);
    __syncthreads();
    // OA spans T0+4r .. T0+4r+3
    #pragma unroll
    for (int k = 0; k < SPR; ++k) {
      const int s = T0 + SPR*r + k;
      if (s >= 3 && s <= 2047) {       // interior: full mask, constant norm
        const float acc = __half2float(fr[s & 7][tid])
                        + __half2float(fr[(s-1) & 7][tid + 256])
                        + __half2float(fr[(s-2) & 7][tid + 512])
                        + __half2float(fr[(s-3) & 7][tid + 768]);
        outb[256*s + tid - 384] = acc * rn;
      } else if (s <= 2049) {          // edges: masked, exact reference norm
        const int o = 256*s + tid - 384;
        float acc = 0.f, nrm = 0.f;
        #pragma unroll
        for (int i = 0; i < 4; ++i) {
          const int f = s - i;
          if (f >= 0 && f <= 2047) {
            acc += __half2float(fr[f & 7][tid + 256*i]);
            nrm += wsq[i];
          }
        }
        if (o >= 0 && o < 524288) outb[o] = acc / nrm;
      }
    }
    __syncthreads();                   // protect ring slots before rewrite
  }
}

// ---------------------------------------------------------------------------
extern "C" void kernel_launch(void* const* d_in, const int* in_sizes, int n_in,
                              void* d_out, int out_size, void* d_ws, size_t ws_size,
                              hipStream_t stream)
{
  const float* hs     = (const float*)d_in[0];   // (16,2048,512)
  const float* Wm     = (const float*)d_in[1];   // (1026,512)
  const float* bias   = (const float*)d_in[2];   // (1026,)
  const float* window = (const float*)d_in[3];   // (1024,)

  char* base = (char*)d_ws;
  ushort_t* Af     = (ushort_t*)base;                     // 33,554,432 B
  ushort_t* Whi    = (ushort_t*)(base + 33554432);        // 1,048,576 B
  __half*   coeffs = (__half*)(base + 67108864);          // 67,108,864 B

  convert_AB<<<2304, 256, 0, stream>>>(hs, Wm, bias, Af, Whi, coeffs);
  gemm_mfma<<<512,  512, 0, stream>>>(Af, Whi, bias, coeffs);
  fft_oa<<<16 * JB, 256, 0, stream>>>(coeffs, window, (float*)d_out);
}

// Round 21
// 122.814 us; speedup vs baseline: 1.0657x; 1.0657x over previous
//
#include <hip/hip_runtime.h>
#include <hip/hip_fp16.h>
#include <math.h>
#include <stdint.h>

// VocosISTFTHead on MI355X — round-19 configuration (best: 122.9us), reverted
// after round-20's in-place-FFT experiment regressed (same-pointer aliasing
// serialized the DS pipe; occupancy 24->16%).
//  K0 convert_AB: fused. Blocks <2048: hs -> Af fp16 plane + Nyquist spec col
//                 (full f32 dot) -> coeffs slot[1]. Blocks >=2048: W -> tiled
//                 fp16 plane Whi [yb4][kt16][r256][k32].
//  K1 gemm_mfma : spec = hs @ W.T + b via single fp16 MFMA (Af x Whi).
//                 256 rows x 128 pairs, 512 thr / 8 waves, 4-buffer A ring,
//                 barrier every 2 K-steps (even-barrier certification).
//  K2 fft_oa    : fused irfft+window+overlap-add, rolling 8-slot ring, rolled
//                 loop, hoisted twiddles, ping-pong FFT buffers, interior-span
//                 OA fast path. RND=11/JB=47 (752 blocks, 3 blocks/CU).
// coeffs row layout (1024 halves, 2048B aligned): [0]=DC real, [1]=Nyquist real,
//   complex k (k=1..511) at halves [2k, 2k+2).
// ws: [0 : 33.55M) Af | [33.55M : 34.60M) Whi | [67.11M : 134.22M) coeffs fp16

#define FRAMES  32768
#define TWO_PI  6.283185307179586f
#define SPR 4      // spans per round
#define RND 11     // rounds per block (44 spans)
#define JB  47     // blocks per batch (spans 0..2067 >= needed 2050)

typedef unsigned short ushort_t;
typedef __attribute__((ext_vector_type(8))) _Float16 f16x8;
typedef __attribute__((ext_vector_type(4))) float f32x4;

#define GLDS(gp, lp) __builtin_amdgcn_global_load_lds( \
    (const __attribute__((address_space(1))) void*)(gp), \
    (__attribute__((address_space(3))) void*)(lp), 16, 0, 0)

__device__ __forceinline__ float2 f2(float x, float y){ return make_float2(x,y); }
__device__ __forceinline__ float2 cadd(float2 a, float2 b){ return f2(a.x+b.x, a.y+b.y); }
__device__ __forceinline__ float2 csub(float2 a, float2 b){ return f2(a.x-b.x, a.y-b.y); }
__device__ __forceinline__ float2 cmul(float2 a, float2 b){ return f2(a.x*b.x - a.y*b.y, a.x*b.y + a.y*b.x); }

__device__ __forceinline__ uint32_t pack2h(float a, float b) {
  const ushort_t ha = __half_as_ushort(__float2half_rn(a));
  const ushort_t hb = __half_as_ushort(__float2half_rn(b));
  return (uint32_t)ha | ((uint32_t)hb << 16);
}

// ---------------------------------------------------------------------------
// K0: fused A/B conversion (unchanged, verified).
// ---------------------------------------------------------------------------
__global__ __launch_bounds__(256) void convert_AB(
    const float* __restrict__ hs, const float* __restrict__ Wm,
    const float* __restrict__ bias, ushort_t* __restrict__ Af,
    ushort_t* __restrict__ Whi, __half* __restrict__ coeffs)
{
  const int bid = blockIdx.x;
  const int t = threadIdx.x;
  if (bid < 2048) {
    const int r = t >> 4, c = t & 15;
    const int m = bid * 16 + r;
    const float* src = hs + (size_t)m * 512 + c * 32;
    const float* wm  = Wm + (size_t)512  * 512 + c * 32;
    const float* wp  = Wm + (size_t)1025 * 512 + c * 32;

    float v[32];
    #pragma unroll
    for (int i = 0; i < 8; ++i) *(float4*)&v[i*4] = *(const float4*)(src + i*4);

    float dm = 0.f, dp = 0.f;
    #pragma unroll
    for (int i = 0; i < 8; ++i) {
      const float4 a  = *(const float4*)&v[i*4];
      const float4 m4 = *(const float4*)(wm + i*4);
      const float4 p4 = *(const float4*)(wp + i*4);
      dm = fmaf(a.x,m4.x, fmaf(a.y,m4.y, fmaf(a.z,m4.z, fmaf(a.w,m4.w, dm))));
      dp = fmaf(a.x,p4.x, fmaf(a.y,p4.y, fmaf(a.z,p4.z, fmaf(a.w,p4.w, dp))));
    }

    uint32_t hu[16];
    #pragma unroll
    for (int i = 0; i < 16; ++i) hu[i] = pack2h(v[2*i], v[2*i+1]);
    ushort_t* dh = Af + (size_t)m * 512 + c * 32;
    #pragma unroll
    for (int q = 0; q < 4; ++q)
      *(uint4*)(dh + q*8) = make_uint4(hu[4*q], hu[4*q+1], hu[4*q+2], hu[4*q+3]);

    #pragma unroll
    for (int off = 8; off; off >>= 1) {
      dm += __shfl_xor(dm, off, 16);
      dp += __shfl_xor(dp, off, 16);
    }
    if (c == 0) {
      const float sm = dm + bias[512], sp = dp + bias[1025];
      const float mag = fminf(__expf(sm), 100.0f);
      coeffs[(size_t)m * 1024 + 1] = __float2half_rn(mag * __cosf(sp));
    }
  } else {
    const int gid = (bid - 2048) * 256 + t;
    const int sd = gid & 3;
    const int r  = (gid >> 2) & 255;
    const int kt = (gid >> 10) & 15;
    const int yb = gid >> 14;                        // 0..3
    const int srow = (r < 128) ? (yb*128 + r) : (513 + yb*128 + (r - 128));
    const float* src = Wm + (size_t)srow * 512 + kt*32 + sd*8;
    const float4 a = *(const float4*)src;
    const float4 b = *(const float4*)(src + 4);
    const uint4 o = make_uint4(pack2h(a.x,a.y), pack2h(a.z,a.w),
                               pack2h(b.x,b.y), pack2h(b.z,b.w));
    *(uint4*)(Whi + (size_t)gid * 8) = o;
  }
}

// ---------------------------------------------------------------------------
// K1: MFMA GEMM, 256 rows x 128 col-pairs, 512 threads, 4-buffer A ring,
//     barrier every 2 K-steps.
// ---------------------------------------------------------------------------
__global__ __launch_bounds__(512, 2) void gemm_mfma(
    const ushort_t* __restrict__ Af, const ushort_t* __restrict__ Whi,
    const float* __restrict__ bias, __half* __restrict__ coeffs)
{
  __shared__ ushort_t Ab[32768];       // 4 bufs x (256r x 32k) fp16 = 64KB

  const int tid = threadIdx.x;
  const int w = tid >> 6, l = tid & 63;
  const int wr = w >> 2, wc = w & 3;         // wave grid 2M x 4N
  const int lc = l & 15, kg = l >> 4;        // frag row/col, k-octet

  const int bid = blockIdx.x;                // 512 = 8 XCD * 64
  const int swz = (bid & 7) * 64 + (bid >> 3);
  const int mb = swz >> 2, yb = swz & 3;     // 4 consecutive yb per mb per XCD

  uint32_t pa_off[2], lofs[2];
  #pragma unroll
  for (int ch = 0; ch < 2; ++ch) {
    const int g = ch*512 + tid;              // 0..1023
    const int r = g >> 2, sd = g & 3;
    lofs[ch] = r*32 + sd*8;                  // ushort units within a 16KB buf
    const int sl = sd ^ ((r >> 1) & 3);
    pa_off[ch] = (uint32_t)(mb*256 + r)*512 + sl*8;
  }
  uint32_t pb_off[4];
  #pragma unroll
  for (int cf = 0; cf < 4; ++cf) {
    const int rB = ((cf < 2) ? 0 : 128) + wc*32 + (cf & 1)*16 + lc;
    pb_off[cf] = (uint32_t)yb*131072u + rB*32 + kg*8;
  }

  f32x4 acc[8][4];                   // [rf][cf]: cf 0,1 mag; 2,3 phase
  #pragma unroll
  for (int rf = 0; rf < 8; ++rf)
    #pragma unroll
    for (int cf = 0; cf < 4; ++cf)
      #pragma unroll
      for (int q = 0; q < 4; ++q) acc[rf][cf][q] = 0.f;

  const int asl = (kg ^ ((lc >> 1) & 3)) * 8;

  f16x8 p[4], q[4];

#define WAITV2 asm volatile("s_waitcnt vmcnt(2) lgkmcnt(0)" ::: "memory")
#define WAITV4 asm volatile("s_waitcnt vmcnt(4) lgkmcnt(0)" ::: "memory")
#define SB     __builtin_amdgcn_s_barrier()
#define SCH0   __builtin_amdgcn_sched_barrier(0)

#define DSREAD(DST, BASE, RF0) do {                                      \
    _Pragma("unroll")                                                    \
    for (int r4 = 0; r4 < 4; ++r4) {                                     \
      const int rr = wr*128 + ((RF0) + r4)*16 + lc;                      \
      DST[r4] = *(const f16x8*)(&Ab[(BASE) + rr*32 + asl]);              \
    }                                                                    \
  } while (0)

#define MFMA16(FA, RF0, RB) do {                                         \
    __builtin_amdgcn_s_setprio(1);                                       \
    _Pragma("unroll")                                                    \
    for (int r4 = 0; r4 < 4; ++r4)                                       \
      _Pragma("unroll")                                                  \
      for (int cf = 0; cf < 4; ++cf)                                     \
        acc[(RF0)+r4][cf] = __builtin_amdgcn_mfma_f32_16x16x32_f16(      \
            FA[r4], RB[cf], acc[(RF0)+r4][cf], 0, 0, 0);                 \
    __builtin_amdgcn_s_setprio(0);                                       \
  } while (0)

  // Even-barrier certification: WAITV2 (vmcnt(2)+lgkm0) at an even step top
  // retires this wave's staging chunks for buf(kt) AND buf(kt+1) before it
  // arrives; barrier release => both buffers fully staged chip-wide, covering
  // this and the next (odd) step's reads. Odd steps barrier-free. WAR: GLDS
  // at step s targets buf(s-2), whose reads completed before the intervening
  // even barrier (lgkmcnt(0) there).
#define ITER(KT, RBC, RBN, BAR) do {                                     \
    if (BAR) { WAITV2; SB; }                                             \
    DSREAD(p, aR, 0);                                                    \
    if ((KT) < 14) GLDS(Af + pa_off[0] + ((KT)+2)*32, &Ab[aW + lofs[0]]);\
    if ((KT) < 15) {                                                     \
      RBN[0] = *(const f16x8*)(Whi + pb_off[0] + ((KT)+1)*8192);         \
      RBN[1] = *(const f16x8*)(Whi + pb_off[1] + ((KT)+1)*8192);         \
    }                                                                    \
    DSREAD(q, aR, 4);                                                    \
    SCH0;                                                                \
    MFMA16(p, 0, RBC);                                                   \
    if ((KT) < 14) GLDS(Af + pa_off[1] + ((KT)+2)*32, &Ab[aW + lofs[1]]);\
    if ((KT) < 15) {                                                     \
      RBN[2] = *(const f16x8*)(Whi + pb_off[2] + ((KT)+1)*8192);         \
      RBN[3] = *(const f16x8*)(Whi + pb_off[3] + ((KT)+1)*8192);         \
    }                                                                    \
    SCH0;                                                                \
    MFMA16(q, 4, RBC);                                                   \
    { const unsigned t_ = aR; aR = aN; aN = aW; aW = aX; aX = t_; }      \
  } while (0)

  f16x8 rb0[4], rb1[4];
  // prologue: stage A(0)->buf0, A(1)->buf1, B(0)->rb0; certify buf0/buf1.
  GLDS(Af + pa_off[0], &Ab[lofs[0]]);
  GLDS(Af + pa_off[1], &Ab[lofs[1]]);
  GLDS(Af + pa_off[0] + 32, &Ab[8192 + lofs[0]]);
  GLDS(Af + pa_off[1] + 32, &Ab[8192 + lofs[1]]);
  SCH0;
  #pragma unroll
  for (int j = 0; j < 4; ++j) rb0[j] = *(const f16x8*)(Whi + pb_off[j]);
  SCH0;
  WAITV4;                              // retire buf0+buf1 chunks (keep B(0))
  SB;
  unsigned aR = 0, aN = 8192, aW = 16384, aX = 24576;

  ITER(0, rb0, rb1, 0);                // barrier provided by prologue
  ITER(1, rb1, rb0, 0);
  for (int k2 = 1; k2 < 8; ++k2) {
    ITER(2*k2,     rb0, rb1, 1);
    ITER(2*k2 + 1, rb1, rb0, 0);
  }
#undef ITER
#undef DSREAD
#undef MFMA16

  // Epilogue: j innermost so both 64B halves of each 128B line are adjacent.
  const int pc0 = yb*128 + wc*32 + lc;               // j=0 col, 0..511
  const int pc1 = pc0 + 16;                          // j=1 col, never 0
  const float bm0 = bias[pc0], bp0 = bias[513 + pc0];
  const float bm1 = bias[pc1], bp1 = bias[513 + pc1];
  #pragma unroll
  for (int rf = 0; rf < 8; ++rf) {
    const int rbase = mb*256 + wr*128 + rf*16 + kg*4;
    #pragma unroll
    for (int qi = 0; qi < 4; ++qi) {
      __half* row = coeffs + (size_t)(rbase + qi) * 1024;
      {
        const float sm = acc[rf][0][qi] + bm0;
        const float sp = acc[rf][2][qi] + bp0;
        const float mag = fminf(__expf(sm), 100.0f);
        const float aa = mag * __cosf(sp);
        const float bb = mag * __sinf(sp);
        if (pc0 == 0) row[0] = __float2half_rn(aa);  // DC real (imag dropped)
        else *(__half2*)(row + 2*pc0) = __float22half2_rn(make_float2(aa, bb));
      }
      {
        const float sm = acc[rf][1][qi] + bm1;
        const float sp = acc[rf][3][qi] + bp1;
        const float mag = fminf(__expf(sm), 100.0f);
        const float aa = mag * __cosf(sp);
        const float bb = mag * __sinf(sp);
        *(__half2*)(row + 2*pc1) = __float22half2_rn(make_float2(aa, bb));
      }
    }
  }
}

// ---------------------------------------------------------------------------
// K2: fused irfft + window + overlap-add (round-18 structure: ping-pong FFT
// buffers, rolled loop, hoisted twiddles, interior OA fast path).
// ---------------------------------------------------------------------------
#define PIDX(s) ((s) + ((s) >> 3))
#define WFENCE  __builtin_amdgcn_wave_barrier()

template<int NS>
__device__ __forceinline__ void stage_fft(const float2* in, float2* out, int l,
                                          const float2* pw)
{
  float2 v[8];
  #pragma unroll
  for (int r = 0; r < 8; ++r) v[r] = in[PIDX(l + 64*r)];
  if (NS > 1) {
    #pragma unroll
    for (int r = 1; r < 8; ++r) v[r] = cmul(v[r], pw[r-1]);
  }
  const float2 e0=v[0], e1=v[2], e2=v[4], e3=v[6];
  const float2 o0=v[1], o1=v[3], o2=v[5], o3=v[7];
  float2 a = cadd(e0,e2), b = csub(e0,e2), c = cadd(e1,e3), d = csub(e1,e3);
  const float2 E0 = cadd(a,c), E2 = csub(a,c);
  const float2 E1 = f2(b.x - d.y, b.y + d.x), E3 = f2(b.x + d.y, b.y - d.x);
  a = cadd(o0,o2); b = csub(o0,o2); c = cadd(o1,o3); d = csub(o1,o3);
  const float2 O0 = cadd(a,c), O2 = csub(a,c);
  const float2 O1 = f2(b.x - d.y, b.y + d.x), O3 = f2(b.x + d.y, b.y - d.x);
  const float r2 = 0.70710678118654752f;
  const float2 t0 = O0;
  const float2 t1 = f2(r2*(O1.x - O1.y),  r2*(O1.x + O1.y));
  const float2 t2 = f2(-O2.y, O2.x);
  const float2 t3 = f2(-r2*(O3.x + O3.y), r2*(O3.x - O3.y));
  float2 X[8];
  X[0]=cadd(E0,t0); X[4]=csub(E0,t0);
  X[1]=cadd(E1,t1); X[5]=csub(E1,t1);
  X[2]=cadd(E2,t2); X[6]=csub(E2,t2);
  X[3]=cadd(E3,t3); X[7]=csub(E3,t3);
  const int idxD = (l / NS) * (NS * 8) + (l & (NS-1));
  #pragma unroll
  for (int q = 0; q < 8; ++q) out[PIDX(idxD + q*NS)] = X[q];
}

// Last stage (NS=64): windowed fp16 pairs straight into the ring slot.
__device__ __forceinline__ void stage_last(const float2* in, __half* frout,
                                           const float* __restrict__ window, int l,
                                           const float2* pw)
{
  float2 v[8];
  #pragma unroll
  for (int r = 0; r < 8; ++r) v[r] = in[PIDX(l + 64*r)];
  #pragma unroll
  for (int r = 1; r < 8; ++r) v[r] = cmul(v[r], pw[r-1]);
  const float2 e0=v[0], e1=v[2], e2=v[4], e3=v[6];
  const float2 o0=v[1], o1=v[3], o2=v[5], o3=v[7];
  float2 a = cadd(e0,e2), b = csub(e0,e2), c = cadd(e1,e3), d = csub(e1,e3);
  const float2 E0 = cadd(a,c), E2 = csub(a,c);
  const float2 E1 = f2(b.x - d.y, b.y + d.x), E3 = f2(b.x + d.y, b.y - d.x);
  a = cadd(o0,o2); b = csub(o0,o2); c = cadd(o1,o3); d = csub(o1,o3);
  const float2 O0 = cadd(a,c), O2 = csub(a,c);
  const float2 O1 = f2(b.x - d.y, b.y + d.x), O3 = f2(b.x + d.y, b.y - d.x);
  const float r2 = 0.70710678118654752f;
  const float2 t0 = O0;
  const float2 t1 = f2(r2*(O1.x - O1.y),  r2*(O1.x + O1.y));
  const float2 t2 = f2(-O2.y, O2.x);
  const float2 t3 = f2(-r2*(O3.x + O3.y), r2*(O3.x - O3.y));
  float2 X[8];
  X[0]=cadd(E0,t0); X[4]=csub(E0,t0);
  X[1]=cadd(E1,t1); X[5]=csub(E1,t1);
  X[2]=cadd(E2,t2); X[6]=csub(E2,t2);
  X[3]=cadd(E3,t3); X[7]=csub(E3,t3);
  #pragma unroll
  for (int q = 0; q < 8; ++q) {
    const int m = l + 64*q;
    const float2 wv = *(const float2*)(window + 2*m);
    *(__half2*)&frout[2*m] =
        __float22half2_rn(make_float2(X[q].x * wv.x, X[q].y * wv.y));
  }
}

__device__ __forceinline__ void fft_frame(const __half* __restrict__ cb, int F,
                                          float2* bAw, float2* bBw,
                                          __half (*fr)[1024],
                                          const float2* twp, const float2* pw8,
                                          const float2* pwL,
                                          const float* __restrict__ window, int l)
{
  if (F < 0 || F > 2047) return;     // wave-uniform; stale slot never read
  const __half2* crow = (const __half2*)(cb + (size_t)F * 1024);
  const float sc = 1.0f / 1024.0f;
  #pragma unroll
  for (int jj = 0; jj < 4; ++jj) {
    const int k = 1 + l + 64*jj;
    const float2 Ck = __half22float2(crow[k]);
    const float2 Cq = __half22float2(crow[512-k]);
    const float cs = twp[jj].x, sn = twp[jj].y;
    const float Ex = sc*(Ck.x + Cq.x), Ey = sc*(Ck.y - Cq.y);
    const float Dx = Ck.x - Cq.x,      Dy = Ck.y + Cq.y;
    const float Ox = sc*(cs*Dx - sn*Dy), Oy = sc*(cs*Dy + sn*Dx);
    bAw[PIDX(k)]     = f2(Ex - Oy, Ey + Ox);
    bAw[PIDX(512-k)] = f2(Ex + Oy, Ox - Ey);
  }
  if (l == 0) {
    const float2 dn = __half22float2(crow[0]);   // (DC real, Nyq real)
    bAw[PIDX(0)] = f2(sc*(dn.x + dn.y), sc*(dn.x - dn.y));
  }
  WFENCE;
  stage_fft<1>(bAw, bBw, l, pw8);
  WFENCE;
  stage_fft<8>(bBw, bAw, l, pw8);
  WFENCE;
  stage_last(bAw, fr[F & 7], window, l, pwL);
  WFENCE;
}

__global__ __launch_bounds__(256) void fft_oa(
    const __half* __restrict__ coeffs, const float* __restrict__ window,
    float* __restrict__ out)
{
  __shared__ float2 bA[4][576];        // 18KB: per-wave FFT scratch
  __shared__ float2 bB[4][576];        // 18KB
  __shared__ __half fr[8][1024];       // 16KB: windowed-frame ring

  const int tid = threadIdx.x;
  const int w = tid >> 6, l = tid & 63;
  const int bid = blockIdx.x;
  const int b = bid / JB, j = bid - b * JB;
  const int T0 = SPR * RND * j;        // first span of this block

  const __half* cb = coeffs + (size_t)b * 2048 * 1024;
  float* outb = out + (size_t)b * 524288;

  // hoisted frame-invariant twiddles (18 sincos once per kernel)
  float2 twp[4], pw8[7], pwL[7];
  #pragma unroll
  for (int jj = 0; jj < 4; ++jj) {
    float sn, cs;
    __sincosf(TWO_PI * (1.0f/1024.0f) * (float)(1 + l + 64*jj), &sn, &cs);
    twp[jj] = f2(cs, sn);
  }
  {
    const float a8 = TWO_PI * (float)(l & 7) / 64.0f;
    const float aL = TWO_PI * (float)l / 512.0f;
    #pragma unroll
    for (int r = 1; r < 8; ++r) {
      float sn, cs;
      __sincosf(a8 * (float)r, &sn, &cs); pw8[r-1] = f2(cs, sn);
    }
    #pragma unroll
    for (int r = 1; r < 8; ++r) {
      float sn, cs;
      __sincosf(aL * (float)r, &sn, &cs); pwL[r-1] = f2(cs, sn);
    }
  }
  float wsq[4];
  #pragma unroll
  for (int i = 0; i < 4; ++i) {
    const float wv = window[tid + 256*i];
    wsq[i] = wv * wv;
  }
  const float rn = 1.0f / (wsq[0] + wsq[1] + wsq[2] + wsq[3]);  // interior norm

  // prologue: frames T0-3..T0-1 (waves 0-2)
  if (w < 3) fft_frame(cb, T0 - 3 + w, bA[w], bB[w], fr, twp, pw8, pwL, window, l);

  for (int r = 0; r < RND; ++r) {
    // compute frames T0+4r+w into ring
    fft_frame(cb, T0 + SPR*r + w, bA[w], bB[w], fr, twp, pw8, pwL, window, l);
    __syncthreads();
    // OA spans T0+4r .. T0+4r+3
    #pragma unroll
    for (int k = 0; k < SPR; ++k) {
      const int s = T0 + SPR*r + k;
      if (s >= 3 && s <= 2047) {       // interior: full mask, constant norm
        const float acc = __half2float(fr[s & 7][tid])
                        + __half2float(fr[(s-1) & 7][tid + 256])
                        + __half2float(fr[(s-2) & 7][tid + 512])
                        + __half2float(fr[(s-3) & 7][tid + 768]);
        outb[256*s + tid - 384] = acc * rn;
      } else if (s <= 2049) {          // edges: masked, exact reference norm
        const int o = 256*s + tid - 384;
        float acc = 0.f, nrm = 0.f;
        #pragma unroll
        for (int i = 0; i < 4; ++i) {
          const int f = s - i;
          if (f >= 0 && f <= 2047) {
            acc += __half2float(fr[f & 7][tid + 256*i]);
            nrm += wsq[i];
          }
        }
        if (o >= 0 && o < 524288) outb[o] = acc / nrm;
      }
    }
    __syncthreads();                   // protect ring slots before rewrite
  }
}

// ---------------------------------------------------------------------------
extern "C" void kernel_launch(void* const* d_in, const int* in_sizes, int n_in,
                              void* d_out, int out_size, void* d_ws, size_t ws_size,
                              hipStream_t stream)
{
  const float* hs     = (const float*)d_in[0];   // (16,2048,512)
  const float* Wm     = (const float*)d_in[1];   // (1026,512)
  const float* bias   = (const float*)d_in[2];   // (1026,)
  const float* window = (const float*)d_in[3];   // (1024,)

  char* base = (char*)d_ws;
  ushort_t* Af     = (ushort_t*)base;                     // 33,554,432 B
  ushort_t* Whi    = (ushort_t*)(base + 33554432);        // 1,048,576 B
  __half*   coeffs = (__half*)(base + 67108864);          // 67,108,864 B

  convert_AB<<<2304, 256, 0, stream>>>(hs, Wm, bias, Af, Whi, coeffs);
  gemm_mfma<<<512,  512, 0, stream>>>(Af, Whi, bias, coeffs);
  fft_oa<<<16 * JB, 256, 0, stream>>>(coeffs, window, (float*)d_out);
}